// Round 10
// baseline (229.758 us; speedup 1.0000x reference)
//
#include <hip/hip_runtime.h>
#include <hip/hip_bf16.h>
#include <math.h>

#define DIM 128

typedef __bf16 bf8 __attribute__((ext_vector_type(8)));
typedef float f4 __attribute__((ext_vector_type(4)));
typedef float f2 __attribute__((ext_vector_type(2)));

struct __align__(8) bf16x4 { __hip_bfloat162 a, b; };

// ---- merged prep: sigmoid(rel)->bf16 (+zero row R), Wcat bf16, W_rel^T,
//      zero offs, sentinel-prefill spack2 ----
__global__ __launch_bounds__(256) void prep_kernel(
    const float* __restrict__ rel,
    const float* __restrict__ Ws,
    const float* __restrict__ Wn,
    const float* __restrict__ Wr,
    __hip_bfloat16* __restrict__ sigb,
    __hip_bfloat16* __restrict__ Wcat,
    float* __restrict__ Wt_rel,
    int* __restrict__ offs,
    uint2* __restrict__ spack2,
    int nSig, int nSigTot, int sigBlocks, int N, int R,
    int zeroBlocks, int fillQuads) {
    int b = blockIdx.x;
    if (b < sigBlocks) {
        int i = b * 256 + threadIdx.x;
        if (i < nSigTot) {
            float v = 0.f;                       // row R is all zeros (sentinel gate)
            if (i < nSig) {
                float x = rel[i];
                v = 1.0f / (1.0f + expf(-x));
            }
            sigb[i] = __float2bfloat16(v);
        }
    } else if (b < sigBlocks + 32) {
        int idx = (b - sigBlocks) * 256 + threadIdx.x;   // 0..8191, 4 elems each
        int j  = idx >> 6;
        int k0 = (idx & 63) * 4;
        const float* src = (k0 < DIM) ? &Ws[j * DIM + k0] : &Wn[j * DIM + (k0 - DIM)];
        float4 v = *(const float4*)src;
        bf16x4 o;
        o.a.x = __float2bfloat16(v.x);
        o.a.y = __float2bfloat16(v.y);
        o.b.x = __float2bfloat16(v.z);
        o.b.y = __float2bfloat16(v.w);
        *(bf16x4*)&Wcat[(size_t)j * 256 + k0] = o;
    } else if (b < sigBlocks + 32 + 64) {
        int id = (b - sigBlocks - 32) * 256 + threadIdx.x;  // 0..16383
        int k = id >> 7;
        int j = id & 127;
        Wt_rel[id] = Wr[j * DIM + k];
    } else if (b < sigBlocks + 32 + 64 + zeroBlocks) {
        int i = (b - sigBlocks - 32 - 64) * 256 + threadIdx.x;
        if (i <= N) offs[i] = 0;
    } else {
        // sentinel prefill: {src_byteoff=0, gate_byteoff=R*256 (zero row)}
        int i = (b - sigBlocks - 32 - 64 - zeroBlocks) * 256 + threadIdx.x;
        if (i < fillQuads) {
            unsigned gz = (unsigned)R * 256u;
            uint4 s; s.x = 0u; s.y = gz; s.z = 0u; s.w = gz;
            ((uint4*)spack2)[i] = s;             // 2 slots per thread
        }
    }
}

// ---- merged: dst histogram w/ rank capture (FIRST, latency-bound)
//      + ent fp32 -> xcat bf16 cols 0..127 (after, BW-bound, hides the atomics) ----
__global__ __launch_bounds__(256) void conv_hist_kernel(
    const float* __restrict__ ent,
    __hip_bfloat16* __restrict__ xcat,
    const int* __restrict__ edge_index,
    int* __restrict__ counts,
    int* __restrict__ rank,
    int N, int E, int histBlocks) {
    if ((int)blockIdx.x < histBlocks) {
        int e = blockIdx.x * 256 + threadIdx.x;
        if (e < E) {
            rank[e] = atomicAdd(&counts[edge_index[E + e]], 1);
        }
    } else {
        long long tid = (long long)(blockIdx.x - histBlocks) * 256 + threadIdx.x;
        int row = (int)(tid >> 5);
        int q   = (int)(tid & 31);
        if (row >= N) return;
        float4 v = *(const float4*)&ent[(size_t)row * DIM + q * 4];
        bf16x4 o;
        o.a.x = __float2bfloat16(v.x);
        o.a.y = __float2bfloat16(v.y);
        o.b.x = __float2bfloat16(v.z);
        o.b.y = __float2bfloat16(v.w);
        *(bf16x4*)&xcat[(size_t)row * 256 + q * 4] = o;
    }
}

// ---- scan pass 1: per-1024-chunk exclusive scan of PADDED (x8) counts ----
#define SCAN_TPB 256
#define SCAN_IPT 4
#define SCAN_IPB 1024

__global__ void scan_pass1(int* __restrict__ data,
                           int* __restrict__ blockSums, int N) {
    __shared__ int ts[SCAN_TPB];
    int t = threadIdx.x;
    int base = blockIdx.x * SCAN_IPB + t * SCAN_IPT;
    int v[SCAN_IPT];
    int s = 0;
    #pragma unroll
    for (int i = 0; i < SCAN_IPT; ++i) {
        int idx = base + i;
        int c = (idx < N) ? data[idx] : 0;
        v[i] = (c + 7) & ~7;                  // pad each segment to x8
        s += v[i];
    }
    ts[t] = s;
    __syncthreads();
    for (int off = 1; off < SCAN_TPB; off <<= 1) {
        int x = (t >= off) ? ts[t - off] : 0;
        __syncthreads();
        ts[t] += x;
        __syncthreads();
    }
    int excl = ts[t] - s;
    #pragma unroll
    for (int i = 0; i < SCAN_IPT; ++i) {
        int idx = base + i;
        if (idx < N) data[idx] = excl;
        excl += v[i];
    }
    if (t == SCAN_TPB - 1) blockSums[blockIdx.x] = ts[t];
}

// ---- scan finish: each block locally scans the <=128 block sums, applies ----
__global__ __launch_bounds__(256) void scan_finish_kernel(
    int* __restrict__ offs, const int* __restrict__ blockSums,
    int nb, int N) {
    __shared__ int ps[128];
    __shared__ int eps[128];
    int t = threadIdx.x;
    int v = 0;
    if (t < 128) {
        v = (t < nb) ? blockSums[t] : 0;
        ps[t] = v;
    }
    __syncthreads();
    for (int off = 1; off < 128; off <<= 1) {
        int x = (t >= off && t < 128) ? ps[t - off] : 0;
        __syncthreads();
        if (t < 128) ps[t] += x;
        __syncthreads();
    }
    if (t < 128) eps[t] = ps[t] - v;   // exclusive prefix of block sums
    __syncthreads();
    int i = blockIdx.x * 256 + t;
    if (i < N)  offs[i] += eps[i >> 10];
    if (i == N) offs[N] = ps[127];     // total PADDED edge-slot count
}

// ---- scatter pre-shifted byte offsets: ATOMIC-FREE, p = offs[dst] + rank[e] ----
__global__ void scatter_ids_kernel(const int* __restrict__ edge_index,
                                   const int* __restrict__ edge_type,
                                   const int* __restrict__ offs,
                                   const int* __restrict__ rank,
                                   uint2* __restrict__ spack2, int E) {
    int e = blockIdx.x * blockDim.x + threadIdx.x;
    if (e >= E) return;
    int dst = edge_index[E + e];
    int p = offs[dst] + rank[e];
    uint2 w;
    w.x = (unsigned)edge_index[e] << 9;    // xcat row byte offset (512 B rows)
    w.y = (unsigned)edge_type[e] << 8;     // sigb row byte offset (256 B rows)
    spack2[p] = w;
}

// ---- relout blocks FIRST (overlap under agg wave stream), then
//      aggregation: 1 wave/node, HALF-WAVE SLOT SPLIT (lanes 0-31 slots
//      e..e+3 @ 4 cols x 8B, lanes 32-63 slots e+4..e+7), 8 sentinel-padded
//      slots/iter, uniform loop, zero per-slot control flow ----
__global__ __launch_bounds__(256) void agg_relout_kernel(
    const __hip_bfloat16* __restrict__ xcat,
    const __hip_bfloat16* __restrict__ sigb,
    const int* __restrict__ offs,
    const uint2* __restrict__ spack2,
    __hip_bfloat16* __restrict__ xcat_w,
    const float* __restrict__ rel,
    const float* __restrict__ Wt_rel,
    const float* __restrict__ b_rel,
    float* __restrict__ out_rel,
    int N, int R, int relBlocks) {
    if ((int)blockIdx.x >= relBlocks) {
        int bid  = blockIdx.x - relBlocks;
        int wid  = bid * 4 + (threadIdx.x >> 6);
        int lane = threadIdx.x & 63;
        if (wid >= N) return;
        int h = lane >> 5;                     // half id -> slot group
        int s = lane & 31;                     // sublane -> cols 4s..4s+3
        unsigned so = (unsigned)s * 8;         // byte offset (bf16x4) in both tables
        // wave-uniform bounds (multiples of 8 by construction)
        int beg = __builtin_amdgcn_readfirstlane(offs[wid]);
        int end = __builtin_amdgcn_readfirstlane(offs[wid + 1]);
        const char* xb = (const char*)xcat;
        const char* gb = (const char*)sigb;
        float a0 = 0.f, a1 = 0.f, a2 = 0.f, a3 = 0.f;
        for (int e = beg; e < end; e += 8) {
            const uint4* qp = (const uint4*)(spack2 + e + 4 * h);
            uint4 qA = qp[0];                  // this half's slots 0,1
            uint4 qB = qp[1];                  // this half's slots 2,3
            #define SLOT(px, py) { \
                bf16x4 v = *(const bf16x4*)(xb + (px + so)); \
                bf16x4 g = *(const bf16x4*)(gb + (py + so)); \
                a0 += __bfloat162float(v.a.x) * __bfloat162float(g.a.x); \
                a1 += __bfloat162float(v.a.y) * __bfloat162float(g.a.y); \
                a2 += __bfloat162float(v.b.x) * __bfloat162float(g.b.x); \
                a3 += __bfloat162float(v.b.y) * __bfloat162float(g.b.y); }
            SLOT(qA.x, qA.y);
            SLOT(qA.z, qA.w);
            SLOT(qB.x, qB.y);
            SLOT(qB.z, qB.w);
            #undef SLOT
        }
        // combine halves (disjoint slots, same columns)
        a0 += __shfl_xor(a0, 32);
        a1 += __shfl_xor(a1, 32);
        a2 += __shfl_xor(a2, 32);
        a3 += __shfl_xor(a3, 32);
        if (h == 0) {
            bf16x4 o;
            o.a.x = __float2bfloat16(a0);
            o.a.y = __float2bfloat16(a1);
            o.b.x = __float2bfloat16(a2);
            o.b.y = __float2bfloat16(a3);
            *(bf16x4*)&xcat_w[(size_t)wid * 256 + 128 + s * 4] = o;
        }
    } else {
        // relout: 2 rel rows per block
        __shared__ float rr[2][DIM];
        int idx  = blockIdx.x;                 // 0 .. R/2-1
        int half = threadIdx.x >> 7;           // 0 or 1
        int col  = threadIdx.x & 127;
        int row  = idx * 2 + half;
        if (row < R) rr[half][col] = rel[(size_t)row * DIM + col];
        __syncthreads();
        if (row >= R) return;
        float acc = b_rel[col];
        #pragma unroll 8
        for (int k = 0; k < DIM; ++k) {
            acc += rr[half][k] * Wt_rel[k * DIM + col];
        }
        out_rel[(size_t)row * DIM + col] = acc;
    }
}

// ---- out_ent = relu(xcat @ Wcat^T + bias) via bf16 MFMA, D = W·X^T order ----
__global__ __launch_bounds__(256) void gemm_mfma_kernel(
    const __hip_bfloat16* xcat,                // [N][256] bf16 (aliases out)
    const __hip_bfloat16* __restrict__ Wcat,   // [128][256] bf16
    const float* __restrict__ b_self,
    const float* __restrict__ b_nei,
    float* out, int N) {
    __shared__ __hip_bfloat16 Bs[128][264];    // +8 pad; SQ_LDS_BANK_CONFLICT measured 0

    int t    = threadIdx.x;
    int wave = t >> 6;
    int lane = t & 63;
    int quad = lane >> 4;
    int r16  = lane & 15;

    {
        int r = t >> 1, h = t & 1;
        const float4* src = (const float4*)&Wcat[(size_t)r * 256 + h * 128];
        #pragma unroll
        for (int i = 0; i < 16; ++i) {
            *(float4*)&Bs[r][h * 128 + i * 8] = src[i];
        }
    }
    __syncthreads();

    int row0 = blockIdx.x * 128 + wave * 32;

    bf8 x[2][8];
    #pragma unroll
    for (int mt = 0; mt < 2; ++mt) {
        int m = row0 + mt * 16 + r16;
        if (m > N - 1) m = N - 1;               // clamp (store guarded below)
        const __hip_bfloat16* xp = &xcat[(size_t)m * 256 + quad * 8];
        #pragma unroll
        for (int ks = 0; ks < 8; ++ks) {
            x[mt][ks] = *(const bf8*)(xp + ks * 32);
        }
    }

    f4 acc[2][8];
    #pragma unroll
    for (int mt = 0; mt < 2; ++mt)
        #pragma unroll
        for (int jt = 0; jt < 8; ++jt)
            acc[mt][jt] = (f4){0.f, 0.f, 0.f, 0.f};

    #pragma unroll
    for (int ks = 0; ks < 8; ++ks) {
        #pragma unroll
        for (int jt = 0; jt < 8; ++jt) {
            bf8 w = *(const bf8*)&Bs[jt * 16 + r16][ks * 32 + quad * 8];
            acc[0][jt] = __builtin_amdgcn_mfma_f32_16x16x32_bf16(w, x[0][ks], acc[0][jt], 0, 0, 0);
            acc[1][jt] = __builtin_amdgcn_mfma_f32_16x16x32_bf16(w, x[1][ks], acc[1][jt], 0, 0, 0);
        }
    }

    f4 bias4[8];
    #pragma unroll
    for (int jt = 0; jt < 8; ++jt) {
        const float4 bs = *(const float4*)&b_self[jt * 16 + quad * 4];
        const float4 bn = *(const float4*)&b_nei[jt * 16 + quad * 4];
        bias4[jt] = (f4){bs.x + bn.x, bs.y + bn.y, bs.z + bn.z, bs.w + bn.w};
    }

    #pragma unroll
    for (int mt = 0; mt < 2; ++mt) {
        int m = row0 + mt * 16 + r16;
        if (m < N) {
            #pragma unroll
            for (int jt = 0; jt < 8; ++jt) {
                f4 v = acc[mt][jt] + bias4[jt];
                float4 o;
                o.x = fmaxf(v[0], 0.f);
                o.y = fmaxf(v[1], 0.f);
                o.z = fmaxf(v[2], 0.f);
                o.w = fmaxf(v[3], 0.f);
                *(float4*)&out[(size_t)m * DIM + jt * 16 + quad * 4] = o;
            }
        }
    }
}

extern "C" void kernel_launch(void* const* d_in, const int* in_sizes, int n_in,
                              void* d_out, int out_size, void* d_ws, size_t ws_size,
                              hipStream_t stream) {
    const float* ent        = (const float*)d_in[0];
    const float* rel        = (const float*)d_in[1];
    const int*   edge_index = (const int*)d_in[2];
    const int*   edge_type  = (const int*)d_in[3];
    const float* W_self     = (const float*)d_in[4];
    const float* b_self     = (const float*)d_in[5];
    const float* W_nei      = (const float*)d_in[6];
    const float* b_nei      = (const float*)d_in[7];
    const float* W_rel      = (const float*)d_in[8];
    const float* b_rel      = (const float*)d_in[9];

    const int N = in_sizes[0] / DIM;   // 100000
    const int R = in_sizes[1] / DIM;   // 500
    const int E = in_sizes[3];         // 600000

    float* out     = (float*)d_out;
    float* out_rel = out + (size_t)N * DIM;
    __hip_bfloat16* xcat = (__hip_bfloat16*)d_out;     // [N][256] bf16 in-place

    // ---- workspace layout ----
    __hip_bfloat16* sigb = (__hip_bfloat16*)d_ws;                  // (R+1)*DIM bf16
    float* Wt_rel  = (float*)(sigb + (size_t)(R + 1) * DIM);       // DIM*DIM fp32
    __hip_bfloat16* Wcat = (__hip_bfloat16*)(Wt_rel + DIM * DIM);  // 128*256 bf16
    int*   offs    = (int*)(Wcat + 128 * 256);         // N+8 ints
    int*   bsums   = offs + (N + 8);                   // 128 ints
    int*   rank    = bsums + 128;                      // E ints
    uint2* spack2  = (uint2*)(rank + E);               // E + 7N + 32 slots (16B-aligned)

    const int nSig = R * DIM;
    const int nSigTot = (R + 1) * DIM;
    const int sigBlocks = (nSigTot + 255) / 256;
    const int zeroBlocks = (N + 1 + 255) / 256;
    const int fillQuads = (E + 7 * N) / 2 + 16;        // uint4 = 2 slots each
    const int fillBlocks = (fillQuads + 255) / 256;
    const int scanBlocks = (N + SCAN_IPB - 1) / SCAN_IPB;   // 98 <= 128

    // 1. merged preps (sig bf16 + zero row, Wcat bf16, W_rel^T, zero offs, sentinel fill)
    prep_kernel<<<sigBlocks + 32 + 64 + zeroBlocks + fillBlocks, 256, 0, stream>>>(
        rel, W_self, W_nei, W_rel, sigb, Wcat, Wt_rel, offs, spack2,
        nSig, nSigTot, sigBlocks, N, R, zeroBlocks, fillQuads);

    // 2. merged hist (first, latency-bound) + conv(ent->bf16) (after, BW-bound)
    {
        int convBlocks = (int)(((long long)N * 32 + 255) / 256);
        int histBlocks = (E + 255) / 256;
        conv_hist_kernel<<<histBlocks + convBlocks, 256, 0, stream>>>(
            ent, xcat, edge_index, offs, rank, N, E, histBlocks);
    }

    // 3. two-pass scan (padded to x8) -> offsets
    scan_pass1<<<scanBlocks, SCAN_TPB, 0, stream>>>(offs, bsums, N);
    scan_finish_kernel<<<(N + 1 + 255) / 256, 256, 0, stream>>>(
        offs, bsums, scanBlocks, N);

    // 4. atomic-free scatter of pre-shifted byte offsets
    scatter_ids_kernel<<<(E + 255) / 256, 256, 0, stream>>>(
        edge_index, edge_type, offs, rank, spack2, E);

    // 5. relout blocks first, then aggregation -> xcat cols 128..255
    {
        int aggBlocks = (int)(((long long)N * 64 + 255) / 256);
        int relBlocks = (R + 1) / 2;
        agg_relout_kernel<<<relBlocks + aggBlocks, 256, 0, stream>>>(
            xcat, sigb, offs, spack2, xcat, rel, Wt_rel, b_rel, out_rel,
            N, R, relBlocks);
    }

    // 6. fused bf16 MFMA GEMM, in-place over xcat
    {
        int blocks = (N + 127) / 128;
        gemm_mfma_kernel<<<blocks, 256, 0, stream>>>(xcat, Wcat, b_self, b_nei, out, N);
    }
}

// Round 11
// 217.496 us; speedup vs baseline: 1.0564x; 1.0564x over previous
//
#include <hip/hip_runtime.h>
#include <hip/hip_bf16.h>
#include <math.h>

#define DIM 128

typedef __bf16 bf8 __attribute__((ext_vector_type(8)));
typedef float f4 __attribute__((ext_vector_type(4)));
typedef float f2 __attribute__((ext_vector_type(2)));

struct __align__(8) bf16x4 { __hip_bfloat162 a, b; };

// ---- merged prep: sigmoid(rel)->bf16 (+zero row R), Wcat bf16, W_rel^T,
//      zero offs, sentinel-prefill spack2 ----
__global__ __launch_bounds__(256) void prep_kernel(
    const float* __restrict__ rel,
    const float* __restrict__ Ws,
    const float* __restrict__ Wn,
    const float* __restrict__ Wr,
    __hip_bfloat16* __restrict__ sigb,
    __hip_bfloat16* __restrict__ Wcat,
    float* __restrict__ Wt_rel,
    int* __restrict__ offs,
    uint2* __restrict__ spack2,
    int nSig, int nSigTot, int sigBlocks, int N, int R,
    int zeroBlocks, int fillQuads) {
    int b = blockIdx.x;
    if (b < sigBlocks) {
        int i = b * 256 + threadIdx.x;
        if (i < nSigTot) {
            float v = 0.f;                       // row R is all zeros (sentinel gate)
            if (i < nSig) {
                float x = rel[i];
                v = 1.0f / (1.0f + expf(-x));
            }
            sigb[i] = __float2bfloat16(v);
        }
    } else if (b < sigBlocks + 32) {
        int idx = (b - sigBlocks) * 256 + threadIdx.x;   // 0..8191, 4 elems each
        int j  = idx >> 6;
        int k0 = (idx & 63) * 4;
        const float* src = (k0 < DIM) ? &Ws[j * DIM + k0] : &Wn[j * DIM + (k0 - DIM)];
        float4 v = *(const float4*)src;
        bf16x4 o;
        o.a.x = __float2bfloat16(v.x);
        o.a.y = __float2bfloat16(v.y);
        o.b.x = __float2bfloat16(v.z);
        o.b.y = __float2bfloat16(v.w);
        *(bf16x4*)&Wcat[(size_t)j * 256 + k0] = o;
    } else if (b < sigBlocks + 32 + 64) {
        int id = (b - sigBlocks - 32) * 256 + threadIdx.x;  // 0..16383
        int k = id >> 7;
        int j = id & 127;
        Wt_rel[id] = Wr[j * DIM + k];
    } else if (b < sigBlocks + 32 + 64 + zeroBlocks) {
        int i = (b - sigBlocks - 32 - 64) * 256 + threadIdx.x;
        if (i <= N) offs[i] = 0;
    } else {
        // sentinel prefill: {src_byteoff=0, gate_byteoff=R*256 (zero row)}
        int i = (b - sigBlocks - 32 - 64 - zeroBlocks) * 256 + threadIdx.x;
        if (i < fillQuads) {
            unsigned gz = (unsigned)R * 256u;
            uint4 s; s.x = 0u; s.y = gz; s.z = 0u; s.w = gz;
            ((uint4*)spack2)[i] = s;             // 2 slots per thread
        }
    }
}

// ---- merged: dst histogram w/ rank capture (FIRST, latency-bound)
//      + ent fp32 -> xcat bf16 cols 0..127 (after, BW-bound, hides the atomics) ----
__global__ __launch_bounds__(256) void conv_hist_kernel(
    const float* __restrict__ ent,
    __hip_bfloat16* __restrict__ xcat,
    const int* __restrict__ edge_index,
    int* __restrict__ counts,
    int* __restrict__ rank,
    int N, int E, int histBlocks) {
    if ((int)blockIdx.x < histBlocks) {
        int e = blockIdx.x * 256 + threadIdx.x;
        if (e < E) {
            rank[e] = atomicAdd(&counts[edge_index[E + e]], 1);
        }
    } else {
        long long tid = (long long)(blockIdx.x - histBlocks) * 256 + threadIdx.x;
        int row = (int)(tid >> 5);
        int q   = (int)(tid & 31);
        if (row >= N) return;
        float4 v = *(const float4*)&ent[(size_t)row * DIM + q * 4];
        bf16x4 o;
        o.a.x = __float2bfloat16(v.x);
        o.a.y = __float2bfloat16(v.y);
        o.b.x = __float2bfloat16(v.z);
        o.b.y = __float2bfloat16(v.w);
        *(bf16x4*)&xcat[(size_t)row * 256 + q * 4] = o;
    }
}

// ---- scan pass 1: per-1024-chunk exclusive scan of PADDED counts ----
#define SCAN_TPB 256
#define SCAN_IPT 4
#define SCAN_IPB 1024

__global__ void scan_pass1(int* __restrict__ data,
                           int* __restrict__ blockSums, int N) {
    __shared__ int ts[SCAN_TPB];
    int t = threadIdx.x;
    int base = blockIdx.x * SCAN_IPB + t * SCAN_IPT;
    int v[SCAN_IPT];
    int s = 0;
    #pragma unroll
    for (int i = 0; i < SCAN_IPT; ++i) {
        int idx = base + i;
        int c = (idx < N) ? data[idx] : 0;
        v[i] = (c + 3) & ~3;                  // pad each segment to x4
        s += v[i];
    }
    ts[t] = s;
    __syncthreads();
    for (int off = 1; off < SCAN_TPB; off <<= 1) {
        int x = (t >= off) ? ts[t - off] : 0;
        __syncthreads();
        ts[t] += x;
        __syncthreads();
    }
    int excl = ts[t] - s;
    #pragma unroll
    for (int i = 0; i < SCAN_IPT; ++i) {
        int idx = base + i;
        if (idx < N) data[idx] = excl;
        excl += v[i];
    }
    if (t == SCAN_TPB - 1) blockSums[blockIdx.x] = ts[t];
}

// ---- scan finish: each block locally scans the <=128 block sums, applies ----
__global__ __launch_bounds__(256) void scan_finish_kernel(
    int* __restrict__ offs, const int* __restrict__ blockSums,
    int nb, int N) {
    __shared__ int ps[128];
    __shared__ int eps[128];
    int t = threadIdx.x;
    int v = 0;
    if (t < 128) {
        v = (t < nb) ? blockSums[t] : 0;
        ps[t] = v;
    }
    __syncthreads();
    for (int off = 1; off < 128; off <<= 1) {
        int x = (t >= off && t < 128) ? ps[t - off] : 0;
        __syncthreads();
        if (t < 128) ps[t] += x;
        __syncthreads();
    }
    if (t < 128) eps[t] = ps[t] - v;   // exclusive prefix of block sums
    __syncthreads();
    int i = blockIdx.x * 256 + t;
    if (i < N)  offs[i] += eps[i >> 10];
    if (i == N) offs[N] = ps[127];     // total PADDED edge-slot count
}

// ---- scatter pre-shifted byte offsets: ATOMIC-FREE, p = offs[dst] + rank[e] ----
__global__ void scatter_ids_kernel(const int* __restrict__ edge_index,
                                   const int* __restrict__ edge_type,
                                   const int* __restrict__ offs,
                                   const int* __restrict__ rank,
                                   uint2* __restrict__ spack2, int E) {
    int e = blockIdx.x * blockDim.x + threadIdx.x;
    if (e >= E) return;
    int dst = edge_index[E + e];
    int p = offs[dst] + rank[e];
    uint2 w;
    w.x = (unsigned)edge_index[e] << 9;    // xcat row byte offset (512 B rows)
    w.y = (unsigned)edge_type[e] << 8;     // sigb row byte offset (256 B rows)
    spack2[p] = w;
}

// ---- relout blocks FIRST (overlap under agg wave stream), then
//      aggregation: 1 wave/node, 4 sentinel-padded edges/iter, ZERO per-edge
//      control flow, scalar edge stream, SOFTWARE-PIPELINED (prefetch next
//      spack quads under the current iteration's gathers) ----
__global__ __launch_bounds__(256) void agg_relout_kernel(
    const __hip_bfloat16* __restrict__ xcat,
    const __hip_bfloat16* __restrict__ sigb,
    const int* __restrict__ offs,
    const uint2* __restrict__ spack2,
    __hip_bfloat16* __restrict__ xcat_w,
    const float* __restrict__ rel,
    const float* __restrict__ Wt_rel,
    const float* __restrict__ b_rel,
    float* __restrict__ out_rel,
    int N, int R, int relBlocks) {
    if ((int)blockIdx.x >= relBlocks) {
        int bid  = blockIdx.x - relBlocks;
        int wid  = bid * 4 + (threadIdx.x >> 6);
        int lane = threadIdx.x & 63;
        if (wid >= N) return;
        // wave-uniform bounds -> scalar loop + s_load of the edge stream
        int beg = __builtin_amdgcn_readfirstlane(offs[wid]);
        int end = __builtin_amdgcn_readfirstlane(offs[wid + 1]);
        const char* xb = (const char*)xcat;
        const char* gb = (const char*)sigb;
        unsigned so = (unsigned)lane * 4;      // 2 cols/lane, 4 B in both tables
        f2 accA = (f2){0.f, 0.f};
        f2 accB = (f2){0.f, 0.f};
        if (beg < end) {
            // prologue: quads for first iteration
            uint4 q01 = *(const uint4*)(spack2 + beg);
            uint4 q23 = *(const uint4*)(spack2 + beg + 2);
            for (int e = beg; e < end; e += 4) {
                // prefetch next iteration's edge ids (pad region makes this safe)
                uint4 n01 = *(const uint4*)(spack2 + e + 4);
                uint4 n23 = *(const uint4*)(spack2 + e + 6);
                __hip_bfloat162 v0 = *(const __hip_bfloat162*)(xb + (q01.x + so));
                __hip_bfloat162 g0 = *(const __hip_bfloat162*)(gb + (q01.y + so));
                __hip_bfloat162 v1 = *(const __hip_bfloat162*)(xb + (q01.z + so));
                __hip_bfloat162 g1 = *(const __hip_bfloat162*)(gb + (q01.w + so));
                __hip_bfloat162 v2 = *(const __hip_bfloat162*)(xb + (q23.x + so));
                __hip_bfloat162 g2 = *(const __hip_bfloat162*)(gb + (q23.y + so));
                __hip_bfloat162 v3 = *(const __hip_bfloat162*)(xb + (q23.z + so));
                __hip_bfloat162 g3 = *(const __hip_bfloat162*)(gb + (q23.w + so));
                f2 vf0 = (f2){__bfloat162float(v0.x), __bfloat162float(v0.y)};
                f2 gf0 = (f2){__bfloat162float(g0.x), __bfloat162float(g0.y)};
                f2 vf1 = (f2){__bfloat162float(v1.x), __bfloat162float(v1.y)};
                f2 gf1 = (f2){__bfloat162float(g1.x), __bfloat162float(g1.y)};
                f2 vf2 = (f2){__bfloat162float(v2.x), __bfloat162float(v2.y)};
                f2 gf2 = (f2){__bfloat162float(g2.x), __bfloat162float(g2.y)};
                f2 vf3 = (f2){__bfloat162float(v3.x), __bfloat162float(v3.y)};
                f2 gf3 = (f2){__bfloat162float(g3.x), __bfloat162float(g3.y)};
                accA += vf0 * gf0;
                accB += vf1 * gf1;
                accA += vf2 * gf2;
                accB += vf3 * gf3;
                q01 = n01;
                q23 = n23;
            }
        }
        f2 s = accA + accB;
        __hip_bfloat162 o;
        o.x = __float2bfloat16(s.x);
        o.y = __float2bfloat16(s.y);
        *(__hip_bfloat162*)&xcat_w[(size_t)wid * 256 + 128 + lane * 2] = o;
    } else {
        // relout: 2 rel rows per block
        __shared__ float rr[2][DIM];
        int idx  = blockIdx.x;                 // 0 .. R/2-1
        int half = threadIdx.x >> 7;           // 0 or 1
        int col  = threadIdx.x & 127;
        int row  = idx * 2 + half;
        if (row < R) rr[half][col] = rel[(size_t)row * DIM + col];
        __syncthreads();
        if (row >= R) return;
        float acc = b_rel[col];
        #pragma unroll 8
        for (int k = 0; k < DIM; ++k) {
            acc += rr[half][k] * Wt_rel[k * DIM + col];
        }
        out_rel[(size_t)row * DIM + col] = acc;
    }
}

// ---- out_ent = relu(xcat @ Wcat^T + bias) via bf16 MFMA, D = W·X^T order ----
__global__ __launch_bounds__(256) void gemm_mfma_kernel(
    const __hip_bfloat16* xcat,                // [N][256] bf16 (aliases out)
    const __hip_bfloat16* __restrict__ Wcat,   // [128][256] bf16
    const float* __restrict__ b_self,
    const float* __restrict__ b_nei,
    float* out, int N) {
    __shared__ __hip_bfloat16 Bs[128][264];    // +8 pad; SQ_LDS_BANK_CONFLICT measured 0

    int t    = threadIdx.x;
    int wave = t >> 6;
    int lane = t & 63;
    int quad = lane >> 4;
    int r16  = lane & 15;

    {
        int r = t >> 1, h = t & 1;
        const float4* src = (const float4*)&Wcat[(size_t)r * 256 + h * 128];
        #pragma unroll
        for (int i = 0; i < 16; ++i) {
            *(float4*)&Bs[r][h * 128 + i * 8] = src[i];
        }
    }
    __syncthreads();

    int row0 = blockIdx.x * 128 + wave * 32;

    bf8 x[2][8];
    #pragma unroll
    for (int mt = 0; mt < 2; ++mt) {
        int m = row0 + mt * 16 + r16;
        if (m > N - 1) m = N - 1;               // clamp (store guarded below)
        const __hip_bfloat16* xp = &xcat[(size_t)m * 256 + quad * 8];
        #pragma unroll
        for (int ks = 0; ks < 8; ++ks) {
            x[mt][ks] = *(const bf8*)(xp + ks * 32);
        }
    }

    f4 acc[2][8];
    #pragma unroll
    for (int mt = 0; mt < 2; ++mt)
        #pragma unroll
        for (int jt = 0; jt < 8; ++jt)
            acc[mt][jt] = (f4){0.f, 0.f, 0.f, 0.f};

    #pragma unroll
    for (int ks = 0; ks < 8; ++ks) {
        #pragma unroll
        for (int jt = 0; jt < 8; ++jt) {
            bf8 w = *(const bf8*)&Bs[jt * 16 + r16][ks * 32 + quad * 8];
            acc[0][jt] = __builtin_amdgcn_mfma_f32_16x16x32_bf16(w, x[0][ks], acc[0][jt], 0, 0, 0);
            acc[1][jt] = __builtin_amdgcn_mfma_f32_16x16x32_bf16(w, x[1][ks], acc[1][jt], 0, 0, 0);
        }
    }

    f4 bias4[8];
    #pragma unroll
    for (int jt = 0; jt < 8; ++jt) {
        const float4 bs = *(const float4*)&b_self[jt * 16 + quad * 4];
        const float4 bn = *(const float4*)&b_nei[jt * 16 + quad * 4];
        bias4[jt] = (f4){bs.x + bn.x, bs.y + bn.y, bs.z + bn.z, bs.w + bn.w};
    }

    #pragma unroll
    for (int mt = 0; mt < 2; ++mt) {
        int m = row0 + mt * 16 + r16;
        if (m < N) {
            #pragma unroll
            for (int jt = 0; jt < 8; ++jt) {
                f4 v = acc[mt][jt] + bias4[jt];
                float4 o;
                o.x = fmaxf(v[0], 0.f);
                o.y = fmaxf(v[1], 0.f);
                o.z = fmaxf(v[2], 0.f);
                o.w = fmaxf(v[3], 0.f);
                *(float4*)&out[(size_t)m * DIM + jt * 16 + quad * 4] = o;
            }
        }
    }
}

extern "C" void kernel_launch(void* const* d_in, const int* in_sizes, int n_in,
                              void* d_out, int out_size, void* d_ws, size_t ws_size,
                              hipStream_t stream) {
    const float* ent        = (const float*)d_in[0];
    const float* rel        = (const float*)d_in[1];
    const int*   edge_index = (const int*)d_in[2];
    const int*   edge_type  = (const int*)d_in[3];
    const float* W_self     = (const float*)d_in[4];
    const float* b_self     = (const float*)d_in[5];
    const float* W_nei      = (const float*)d_in[6];
    const float* b_nei      = (const float*)d_in[7];
    const float* W_rel      = (const float*)d_in[8];
    const float* b_rel      = (const float*)d_in[9];

    const int N = in_sizes[0] / DIM;   // 100000
    const int R = in_sizes[1] / DIM;   // 500
    const int E = in_sizes[3];         // 600000

    float* out     = (float*)d_out;
    float* out_rel = out + (size_t)N * DIM;
    __hip_bfloat16* xcat = (__hip_bfloat16*)d_out;     // [N][256] bf16 in-place

    // ---- workspace layout ----
    __hip_bfloat16* sigb = (__hip_bfloat16*)d_ws;                  // (R+1)*DIM bf16
    float* Wt_rel  = (float*)(sigb + (size_t)(R + 1) * DIM);       // DIM*DIM fp32
    __hip_bfloat16* Wcat = (__hip_bfloat16*)(Wt_rel + DIM * DIM);  // 128*256 bf16
    int*   offs    = (int*)(Wcat + 128 * 256);         // N+8 ints
    int*   bsums   = offs + (N + 8);                   // 128 ints
    int*   rank    = bsums + 128;                      // E ints
    uint2* spack2  = (uint2*)(rank + E);               // E + 3N + 16 slots (16B-aligned)

    const int nSig = R * DIM;
    const int nSigTot = (R + 1) * DIM;
    const int sigBlocks = (nSigTot + 255) / 256;
    const int zeroBlocks = (N + 1 + 255) / 256;
    const int fillQuads = (E + 3 * N) / 2 + 8;         // uint4 = 2 slots each
    const int fillBlocks = (fillQuads + 255) / 256;
    const int scanBlocks = (N + SCAN_IPB - 1) / SCAN_IPB;   // 98 <= 128

    // 1. merged preps (sig bf16 + zero row, Wcat bf16, W_rel^T, zero offs, sentinel fill)
    prep_kernel<<<sigBlocks + 32 + 64 + zeroBlocks + fillBlocks, 256, 0, stream>>>(
        rel, W_self, W_nei, W_rel, sigb, Wcat, Wt_rel, offs, spack2,
        nSig, nSigTot, sigBlocks, N, R, zeroBlocks, fillQuads);

    // 2. merged hist (first, latency-bound) + conv(ent->bf16) (after, BW-bound)
    {
        int convBlocks = (int)(((long long)N * 32 + 255) / 256);
        int histBlocks = (E + 255) / 256;
        conv_hist_kernel<<<histBlocks + convBlocks, 256, 0, stream>>>(
            ent, xcat, edge_index, offs, rank, N, E, histBlocks);
    }

    // 3. two-pass scan (padded to x4) -> offsets
    scan_pass1<<<scanBlocks, SCAN_TPB, 0, stream>>>(offs, bsums, N);
    scan_finish_kernel<<<(N + 1 + 255) / 256, 256, 0, stream>>>(
        offs, bsums, scanBlocks, N);

    // 4. atomic-free scatter of pre-shifted byte offsets
    scatter_ids_kernel<<<(E + 255) / 256, 256, 0, stream>>>(
        edge_index, edge_type, offs, rank, spack2, E);

    // 5. relout blocks first, then aggregation -> xcat cols 128..255
    {
        int aggBlocks = (int)(((long long)N * 64 + 255) / 256);
        int relBlocks = (R + 1) / 2;
        agg_relout_kernel<<<relBlocks + aggBlocks, 256, 0, stream>>>(
            xcat, sigb, offs, spack2, xcat, rel, Wt_rel, b_rel, out_rel,
            N, R, relBlocks);
    }

    // 6. fused bf16 MFMA GEMM, in-place over xcat
    {
        int blocks = (N + 127) / 128;
        gemm_mfma_kernel<<<blocks, 256, 0, stream>>>(xcat, Wcat, b_self, b_nei, out, N);
    }
}